// Round 13
// baseline (438.751 us; speedup 1.0000x reference)
//
#include <hip/hip_runtime.h>
#include <hip/hip_bf16.h>

using bf16 = __hip_bfloat16;
typedef __attribute__((ext_vector_type(8))) short short8;
typedef __attribute__((ext_vector_type(4))) float f32x4;
typedef __attribute__((ext_vector_type(4))) unsigned short us4;

static constexpr int Bn = 4, Sn = 2048, Dn = 1024;
static constexpr int ROWS = Bn * Sn;  // 8192
static constexpr float EPS = 1e-5f;

__device__ __forceinline__ void splitf(float v, bf16& hi, bf16& lo) {
    hi = __float2bfloat16(v);
    lo = __float2bfloat16(v - __bfloat162float(hi));
}

__device__ __forceinline__ void gload_lds16(const void* g, void* l) {
    __builtin_amdgcn_global_load_lds(
        (__attribute__((address_space(1))) void*)(void*)g,
        (__attribute__((address_space(3))) void*)l, 16, 0, 0);
}

// ---------- weight split -> [hi | lo] planes, row stride 2048 ----------
__global__ __launch_bounds__(256) void wsplit2_kernel(const float* __restrict__ w,
                                                      bf16* __restrict__ out) {
    const int i = blockIdx.x * 256 + threadIdx.x;  // one thread per 4 elems
    const float4 v = reinterpret_cast<const float4*>(w)[i];
    const int row = i >> 8, c = (i & 255) << 2;
    alignas(8) bf16 h[4], l[4];
    splitf(v.x, h[0], l[0]); splitf(v.y, h[1], l[1]);
    splitf(v.z, h[2], l[2]); splitf(v.w, h[3], l[3]);
    bf16* o = out + (size_t)row * 2048 + c;
    *reinterpret_cast<us4*>(o)        = *reinterpret_cast<const us4*>(h);
    *reinterpret_cast<us4*>(o + 1024) = *reinterpret_cast<const us4*>(l);
}

// ---------- weight hi-only split ----------
__global__ __launch_bounds__(256) void wsplit_hi_kernel(const float* __restrict__ w,
                                                        bf16* __restrict__ hi) {
    const int i = blockIdx.x * 256 + threadIdx.x;
    const float4 v = reinterpret_cast<const float4*>(w)[i];
    alignas(8) bf16 h[4];
    bf16 l;
    splitf(v.x, h[0], l); splitf(v.y, h[1], l);
    splitf(v.z, h[2], l); splitf(v.w, h[3], l);
    *reinterpret_cast<us4*>(hi + i * 4) = *reinterpret_cast<const us4*>(h);
}

// ---------- LayerNorm -> h2 [hi | lo] planes, row stride 2048 ----------
__global__ __launch_bounds__(256) void ln2_kernel(const float* __restrict__ x,
                                                  const float* __restrict__ w,
                                                  bf16* __restrict__ h2) {
    const int row = blockIdx.x, tid = threadIdx.x;
    const int lane = tid & 63, wave = tid >> 6;
    const float4 v = reinterpret_cast<const float4*>(x + (size_t)row * Dn)[tid];
    float s  = v.x + v.y + v.z + v.w;
    float s2 = v.x*v.x + v.y*v.y + v.z*v.z + v.w*v.w;
    #pragma unroll
    for (int off = 32; off > 0; off >>= 1) {
        s  += __shfl_down(s,  off, 64);
        s2 += __shfl_down(s2, off, 64);
    }
    __shared__ float red[8];
    if (lane == 0) { red[wave] = s; red[4 + wave] = s2; }
    __syncthreads();
    s  = red[0] + red[1] + red[2] + red[3];
    s2 = red[4] + red[5] + red[6] + red[7];
    const float mu  = s * (1.0f / Dn);
    const float var = s2 * (1.0f / Dn) - mu * mu;
    const float rs  = rsqrtf(var + EPS);
    const float4 wv = reinterpret_cast<const float4*>(w)[tid];
    alignas(8) bf16 h[4], l[4];
    splitf((v.x - mu) * rs * wv.x, h[0], l[0]);
    splitf((v.y - mu) * rs * wv.y, h[1], l[1]);
    splitf((v.z - mu) * rs * wv.z, h[2], l[2]);
    splitf((v.w - mu) * rs * wv.w, h[3], l[3]);
    bf16* o = h2 + (size_t)row * 2048 + tid * 4;
    *reinterpret_cast<us4*>(o)        = *reinterpret_cast<const us4*>(h);
    *reinterpret_cast<us4*>(o + 1024) = *reinterpret_cast<const us4*>(l);
}

// ---------- row softmax (2048 wide), writes plain bf16 P in place ----------
__global__ __launch_bounds__(256) void softmax_kernel(float* __restrict__ scores) {
    const int row = blockIdx.x, tid = threadIdx.x;
    const int lane = tid & 63, wave = tid >> 6;
    float* r = scores + (size_t)row * Sn;
    const float4 v0 = reinterpret_cast<const float4*>(r)[tid];
    const float4 v1 = reinterpret_cast<const float4*>(r)[tid + 256];
    float m = fmaxf(fmaxf(fmaxf(v0.x, v0.y), fmaxf(v0.z, v0.w)),
                    fmaxf(fmaxf(v1.x, v1.y), fmaxf(v1.z, v1.w)));
    #pragma unroll
    for (int off = 32; off > 0; off >>= 1) m = fmaxf(m, __shfl_down(m, off, 64));
    __shared__ float red[8];
    if (lane == 0) red[wave] = m;
    __syncthreads();
    m = fmaxf(fmaxf(red[0], red[1]), fmaxf(red[2], red[3]));
    float e[8];
    e[0] = expf(v0.x - m); e[1] = expf(v0.y - m);
    e[2] = expf(v0.z - m); e[3] = expf(v0.w - m);
    e[4] = expf(v1.x - m); e[5] = expf(v1.y - m);
    e[6] = expf(v1.z - m); e[7] = expf(v1.w - m);
    float s = e[0]+e[1]+e[2]+e[3]+e[4]+e[5]+e[6]+e[7];
    #pragma unroll
    for (int off = 32; off > 0; off >>= 1) s += __shfl_down(s, off, 64);
    if (lane == 0) red[4 + wave] = s;
    __syncthreads();
    s = red[4] + red[5] + red[6] + red[7];
    const float inv = 1.0f / s;
    bf16* hi = reinterpret_cast<bf16*>(r);
    #pragma unroll
    for (int j = 0; j < 4; ++j) hi[tid*4 + j]        = __float2bfloat16(e[j] * inv);
    #pragma unroll
    for (int j = 0; j < 4; ++j) hi[1024 + tid*4 + j] = __float2bfloat16(e[4+j] * inv);
}

// ---------- 128x128 plain bf16 GEMM (C = A @ B^T), 4 waves ----------
// SM: 0 = f32 store, 2 = bf16 transposed store, 3 = bf16 store
template <int SM>
__global__ __launch_bounds__(256)
void gemm3(const bf16* __restrict__ A, int lda, long long sA,
           const bf16* __restrict__ B, int ldb, long long sB,
           float* __restrict__ Cf, bf16* __restrict__ Cb,
           int ldc, long long sC, int K) {
    const int tid = threadIdx.x;
    const int lane = tid & 63, wave = tid >> 6;
    const int bm = blockIdx.x, bn = blockIdx.y;
    const long long aBase = (long long)blockIdx.z * sA;
    const long long bBase = (long long)blockIdx.z * sB;
    const long long cBase = (long long)blockIdx.z * sC;

    __shared__ bf16 sAh[128*32];
    __shared__ bf16 sBh[128*32];

    f32x4 acc[4][4];
    #pragma unroll
    for (int i = 0; i < 4; ++i)
        #pragma unroll
        for (int j = 0; j < 4; ++j) acc[i][j] = f32x4{0.f, 0.f, 0.f, 0.f};

    const int wm = wave >> 1, wn = wave & 1;
    const int fr = lane & 15;
    const int kb = (lane >> 4) * 8;

    for (int k0 = 0; k0 < K; k0 += 32) {
        #pragma unroll
        for (int i = 0; i < 2; ++i) {
            const int idx = (i * 4 + wave) * 64 + lane;
            const int row = idx >> 2;
            const int seg = (idx & 3) * 8;
            const int lds_off = (i * 4 + wave) * 512;  // wave-uniform
            gload_lds16(A + aBase + (long long)(bm * 128 + row) * lda + k0 + seg, sAh + lds_off);
            gload_lds16(B + bBase + (long long)(bn * 128 + row) * ldb + k0 + seg, sBh + lds_off);
        }
        __syncthreads();
        short8 ah[4], bh[4];
        #pragma unroll
        for (int t = 0; t < 4; ++t) {
            ah[t] = *reinterpret_cast<const short8*>(sAh + (wm*64 + t*16 + fr) * 32 + kb);
            bh[t] = *reinterpret_cast<const short8*>(sBh + (wn*64 + t*16 + fr) * 32 + kb);
        }
        #pragma unroll
        for (int mi = 0; mi < 4; ++mi)
            #pragma unroll
            for (int ni = 0; ni < 4; ++ni)
                acc[mi][ni] = __builtin_amdgcn_mfma_f32_16x16x32_bf16(ah[mi], bh[ni], acc[mi][ni], 0, 0, 0);
        __syncthreads();
    }

    #pragma unroll
    for (int mi = 0; mi < 4; ++mi) {
        const int row0 = bm * 128 + wm * 64 + mi * 16 + (lane >> 4) * 4;
        #pragma unroll
        for (int ni = 0; ni < 4; ++ni) {
            const int col = bn * 128 + wn * 64 + ni * 16 + fr;
            if constexpr (SM == 0) {
                #pragma unroll
                for (int r = 0; r < 4; ++r)
                    Cf[cBase + (long long)(row0 + r) * ldc + col] = acc[mi][ni][r];
            } else if constexpr (SM == 2) {
                alignas(8) bf16 th[4];
                #pragma unroll
                for (int r = 0; r < 4; ++r) th[r] = __float2bfloat16(acc[mi][ni][r]);
                const long long o = cBase + (long long)col * ldc + row0;
                *reinterpret_cast<us4*>(Cb + o) = *reinterpret_cast<const us4*>(th);
            } else {
                #pragma unroll
                for (int r = 0; r < 4; ++r)
                    Cb[cBase + (long long)(row0 + r) * ldc + col] = __float2bfloat16(acc[mi][ni][r]);
            }
        }
    }
}

// ---------- 256x256 8-phase split-3 GEMM, K'=3072 over 2-plane storage ----------
// A physical [M][2048] = [Ahi|Alo]; B physical [N][2048] = [Bhi|Blo].
// Logical K = 3072 in three 1024-groups; group g uses A-plane (RA>>g)&1, B-plane (RB>>g)&1.
// SM: 0 = f32 store; 1 = QK epilogue -> q2/k2 [hi|lo] planes.
// 8 waves (2Mx4N), per-wave C 128x64. LDS: 8 slots of 16KB: slot(buf,mat,ks) = 256 rows x 32 k.
// Swizzle: 16B-chunk ^= ((row>>1)&3) — measured 0 bank conflicts (round 3/7).
// vmcnt discipline (fix of round-7's over-eager waits): every even phase ends with
// vmcnt(8), which retires exactly the 2 slots staged 5-6 phases (~1000 cyc) earlier —
// never waits on a load younger than HBM latency (m126: ~900 cyc).
#define G256_PHASE(BUF, KS, MG, READB, ST_T, ST_MAT, ST_KS, VM)                              \
    {                                                                                        \
        const int slotA_ = (((BUF) * 2 + 0) * 2 + (KS)) * 8192;                              \
        const int slotB_ = (((BUF) * 2 + 1) * 2 + (KS)) * 8192;                              \
        if (READB) {                                                                         \
            _Pragma("unroll")                                                                \
            for (int n = 0; n < 4; ++n)                                                      \
                bfr[n] = *reinterpret_cast<const short8*>(lds + slotB_ + boff + n * 512);    \
        }                                                                                    \
        short8 afr[4];                                                                       \
        _Pragma("unroll")                                                                    \
        for (int m = 0; m < 4; ++m)                                                          \
            afr[m] = *reinterpret_cast<const short8*>(lds + slotA_ + aoff + ((MG)*4 + m) * 512); \
        {   /* stage one full slot (2 x gload_lds, 16KB) */                                  \
            const int tc_ = ((ST_T) < 47) ? (ST_T) : 47;                                     \
            const int slot_ = ((((ST_T) & 1) * 2 + (ST_MAT)) * 2 + (ST_KS)) * 8192;          \
            const int R_ = (ST_MAT) ? RB : RA;                                               \
            const int kb_ = (((R_ >> (tc_ >> 4)) & 1) << 10) + ((tc_ & 15) << 6) + ((ST_KS) << 5); \
            const bf16* g_ = (ST_MAT) ? gB : gA;                                             \
            const int ld_ = (ST_MAT) ? ldb : lda;                                            \
            gload_lds16(g_ + (long long)srow * ld_ + kb_ + schunk, lds + slot_ + wave * 512);\
            gload_lds16(g_ + (long long)(128 + srow) * ld_ + kb_ + schunk,                   \
                        lds + slot_ + 4096 + wave * 512);                                    \
        }                                                                                    \
        __builtin_amdgcn_s_barrier();                                                        \
        asm volatile("s_waitcnt lgkmcnt(0)" ::: "memory");                                   \
        __builtin_amdgcn_sched_barrier(0);                                                   \
        __builtin_amdgcn_s_setprio(1);                                                       \
        _Pragma("unroll")                                                                    \
        for (int m = 0; m < 4; ++m)                                                          \
            _Pragma("unroll")                                                                \
            for (int n = 0; n < 4; ++n)                                                      \
                acc[(MG)*4 + m][n] = __builtin_amdgcn_mfma_f32_16x16x32_bf16(                \
                    afr[m], bfr[n], acc[(MG)*4 + m][n], 0, 0, 0);                            \
        __builtin_amdgcn_s_setprio(0);                                                       \
        if (VM) asm volatile("s_waitcnt vmcnt(8)" ::: "memory");                             \
        __builtin_amdgcn_s_barrier();                                                        \
    }

template <int RA, int RB, int SM>
__global__ __launch_bounds__(512, 2)
void gemm256(const bf16* __restrict__ A, int lda, long long sA,
             const bf16* __restrict__ B, int ldb, long long sB,
             float* __restrict__ Cf, bf16* __restrict__ Cq, bf16* __restrict__ Ck,
             int ldc, long long sC) {
    const int tid = threadIdx.x;
    const int lane = tid & 63, wave = tid >> 6;
    const int wm = wave >> 2, wn = wave & 3;
    const int fr = lane & 15, s0 = lane >> 4;
    const int bm = blockIdx.x, bn = blockIdx.y;

    __shared__ bf16 lds[8 * 8192];  // 128 KiB

    const bf16* gA = A + (long long)blockIdx.z * sA + (long long)(bm * 256) * lda;
    const bf16* gB = B + (long long)blockIdx.z * sB + (long long)(bn * 256) * ldb;

    // staging: 4 threads per 64B row-half; covers rows 0-127 / 128-255 per gload pair
    const int srow = tid >> 2;
    const int schunk = (((tid & 3) ^ ((tid >> 3) & 3))) * 8;  // pre-swizzled source chunk

    // read-side fragment offsets (elems); swizzled chunk = s0 ^ ((row>>1)&3)
    const int rsw = (s0 ^ ((fr >> 1) & 3)) * 8;
    const int aoff = (wm * 128 + fr) * 32 + rsw;
    const int boff = (wn * 64 + fr) * 32 + rsw;

    f32x4 acc[8][4];
    #pragma unroll
    for (int i = 0; i < 8; ++i)
        #pragma unroll
        for (int j = 0; j < 4; ++j) acc[i][j] = f32x4{0.f, 0.f, 0.f, 0.f};
    short8 bfr[4];

    // prologue: stage tile0 (buf0, 4 slots) + tile1 ks0 (buf1, 2 slots); wait tile0
    {
        #pragma unroll
        for (int st = 0; st < 6; ++st) {
            const int t_ = (st < 4) ? 0 : 1;
            const int mat_ = st & 1;
            const int ks_ = (st < 4) ? (st >> 1) : 0;
            const int slot_ = (((t_ & 1) * 2 + mat_) * 2 + ks_) * 8192;
            const int R_ = mat_ ? RB : RA;
            const int kb_ = (((R_ >> (t_ >> 4)) & 1) << 10) + ((t_ & 15) << 6) + (ks_ << 5);
            const bf16* g_ = mat_ ? gB : gA;
            const int ld_ = mat_ ? ldb : lda;
            gload_lds16(g_ + (long long)srow * ld_ + kb_ + schunk, lds + slot_ + wave * 512);
            gload_lds16(g_ + (long long)(128 + srow) * ld_ + kb_ + schunk,
                        lds + slot_ + 4096 + wave * 512);
        }
        asm volatile("s_waitcnt vmcnt(4)" ::: "memory");
        __builtin_amdgcn_s_barrier();
    }

    for (int j = 0; j < 24; ++j) {
        const int t0 = 2 * j, t1 = 2 * j + 1;
        // waits: vmcnt(8) at end of EVERY even phase — retires the 2 slots staged
        // 5-6 phases earlier, exactly covering the next two phases' reads.
        G256_PHASE(0, 0, 0, true,  t1,     0, 1, false)
        G256_PHASE(0, 0, 1, false, t1,     1, 1, true)
        G256_PHASE(0, 1, 0, true,  t0 + 2, 0, 0, false)
        G256_PHASE(0, 1, 1, false, t0 + 2, 1, 0, true)
        G256_PHASE(1, 0, 0, true,  t0 + 2, 0, 1, false)
        G256_PHASE(1, 0, 1, false, t0 + 2, 1, 1, true)
        G256_PHASE(1, 1, 0, true,  t1 + 2, 0, 0, false)
        G256_PHASE(1, 1, 1, false, t1 + 2, 1, 0, true)
    }

    const long long cB = (long long)blockIdx.z * sC;
    #pragma unroll
    for (int mi = 0; mi < 8; ++mi) {
        const int row0 = bm * 256 + wm * 128 + mi * 16 + s0 * 4;
        #pragma unroll
        for (int ni = 0; ni < 4; ++ni) {
            const int col = bn * 256 + wn * 64 + ni * 16 + fr;
            if constexpr (SM == 0) {
                #pragma unroll
                for (int r = 0; r < 4; ++r)
                    Cf[cB + (long long)(row0 + r) * ldc + col] = acc[mi][ni][r];
            } else {  // QK epilogue: cols 0-1023 -> q2 [hi|lo], 1024-2047 -> k2 [hi|lo]
                #pragma unroll
                for (int r = 0; r < 4; ++r) {
                    bf16 h, l; splitf(acc[mi][ni][r], h, l);
                    bf16* dst = (col < 1024) ? Cq : Ck;
                    const int c = col & 1023;
                    const long long o = (long long)(row0 + r) * 2048 + c;
                    dst[o] = h; dst[o + 1024] = l;
                }
            }
        }
    }
}

extern "C" void kernel_launch(void* const* d_in, const int* in_sizes, int n_in,
                              void* d_out, int out_size, void* d_ws, size_t ws_size,
                              hipStream_t stream) {
    const float* x    = (const float*)d_in[0];
    const float* ln_w = (const float*)d_in[1];
    const float* wq   = (const float*)d_in[2];
    const float* wk   = (const float*)d_in[3];
    const float* wv   = (const float*)d_in[4];
    const float* wo   = (const float*)d_in[5];
    float* out = (float*)d_out;

    const size_t M1 = 1u << 20;
    bf16* base = (bf16*)d_ws;  // total ws use: 162 MiB
    // region A [0, 32M elems): transient (h2/w2/wv_hi), later f32 scores
    bf16* h2    = base;              // 16M elems: [8192][2048] = [hi|lo]
    bf16* w2    = base + 16*M1;      // 4M: [2048][2048] = [hi|lo], wq rows 0-1023, wk 1024-2047
    bf16* wv_hi = base + 20*M1;      // 1M
    float* scores = (float*)base;    // 16M f32 = 64MB, overlays region A
    // persistent
    bf16* q2    = base + 32*M1;      // 16M: [8192][2048] = [qhi|qlo]
    bf16* k2    = base + 48*M1;      // 16M: [8192][2048] = [khi|klo]
    bf16* vt    = base + 64*M1;      // 8M: [4][1024][2048]
    bf16* ctx   = base + 72*M1;      // 8M
    bf16* wo_hi = base + 80*M1;      // 1M

    // 1. weight splits (wo deferred — not needed until after scores)
    wsplit2_kernel<<<dim3(1024), 256, 0, stream>>>(wq, w2);
    wsplit2_kernel<<<dim3(1024), 256, 0, stream>>>(wk, w2 + (size_t)1024 * 2048);
    wsplit_hi_kernel<<<dim3(1024), 256, 0, stream>>>(wv, wv_hi);

    // 2. LayerNorm -> h2 [hi|lo]
    ln2_kernel<<<ROWS, 256, 0, stream>>>(x, ln_w, h2);

    // 3. [Q|K] = h @ [wq;wk]^T, split-3 via plane remap (hh·wh + hl·wh + hh·wl).
    //    A groups (hh,hl,hh) -> RA=0b010; B groups (wh,wh,wl) -> RB=0b100. grid 32x8
    gemm256<0b010, 0b100, 1><<<dim3(ROWS/256, 2*Dn/256), 512, 0, stream>>>(
        h2, 2048, 0, w2, 2048, 0,
        nullptr, q2, k2, 0, 0);

    // 4. V = h @ wv^T (hi-only), transposed store vt[b][d][s]. grid 16x8x4
    gemm3<2><<<dim3(Sn/128, Dn/128, Bn), 256, 0, stream>>>(
        h2, 2048, (long long)Sn * 2048, wv_hi, 1024, 0,
        nullptr, vt, Sn, (long long)Dn * Sn, 1024);

    // 5. scores = q @ k^T, split-3 (qh·kh + qh·kl + ql·kh).
    //    A groups (qh,qh,ql) -> RA=0b100; B groups (kh,kl,kh) -> RB=0b010. grid 8x8x4
    gemm256<0b100, 0b010, 0><<<dim3(Sn/256, Sn/256, Bn), 512, 0, stream>>>(
        q2, 2048, (long long)Sn * 2048, k2, 2048, (long long)Sn * 2048,
        scores, nullptr, nullptr, Sn, (long long)Sn * Sn);

    // 6. softmax rows -> plain bf16 P in place (row stride 4096 bf16)
    softmax_kernel<<<ROWS, 256, 0, stream>>>(scores);

    // 7. wo split (transient region for it is free now)
    wsplit_hi_kernel<<<dim3(1024), 256, 0, stream>>>(wo, wo_hi);

    // 8. ctx = P @ vt. grid 16x8x4
    gemm3<3><<<dim3(Sn/128, Dn/128, Bn), 256, 0, stream>>>(
        (const bf16*)scores, 2*Sn, (long long)Sn * 2*Sn,
        vt, Sn, (long long)Dn * Sn,
        nullptr, ctx, Dn, (long long)Sn * Dn, Sn);

    // 9. out = ctx @ wo^T (f32 -> d_out). grid 64x8
    gemm3<0><<<dim3(ROWS/128, Dn/128), 256, 0, stream>>>(
        ctx, Dn, 0, wo_hi, Dn, 0,
        out, nullptr, Dn, 0, Dn);
}